// Round 7
// baseline (428.063 us; speedup 1.0000x reference)
//
#include <hip/hip_runtime.h>

typedef short short8 __attribute__((ext_vector_type(8)));
typedef float f32x4 __attribute__((ext_vector_type(4)));

#define HW_   (512 * 512)
#define B_    4
#define D_    64
#define NPIX  (B_ * HW_)          // 1048576
#define NW    19                  // within labels (20 - 1)
#define NLAB  45                  // 19 within + 26 cross
#define NSEG  20
#define THREADS 256
#define TILES 8                   // pixel tiles per block
#define BLKPIX (THREADS * TILES)  // 2048 (divides HW_)
#define NBLK  (NPIX / BLKPIX)     // 512

__device__ __forceinline__ unsigned short f2bf(float x) {   // RNE f32->bf16
    unsigned u = __float_as_uint(x);
    return (unsigned short)((u + 0x7FFFu + ((u >> 16) & 1u)) >> 16);
}

// B-fragments in d_ws: frag q = t*2+s (t=N-tile 0..2, s=K-step 0..1).
// wsB[q*512 + l*8 + j] = W[col = (q>>1)*16 + (l&15)][k = (q&1)*32 + (l>>4)*8 + j]
// (same (l,j)->k map as the A-frag reads below; any k-permutation cancels in A*B)
__global__ void prep_b(const float* __restrict__ wW, const float* __restrict__ wC,
                       unsigned short* __restrict__ wsB) {
    int tid = threadIdx.x;
    for (int kk = 0; kk < 12; ++kk) {
        int idx = tid + kk * 256;              // 0..3071
        int q = idx >> 9, rem = idx & 511;
        int l = rem >> 3, j = rem & 7;
        int col = (q >> 1) * 16 + (l & 15);
        int kch = (q & 1) * 32 + ((l >> 4) * 8) + j;
        float v = 0.f;
        if (col < NW) v = wW[col * D_ + kch];
        else if (col < NLAB) v = wC[(col - NW) * D_ + kch];
        wsB[idx] = f2bf(v);                    // padded cols 45..47 -> 0 (masked in entropy)
    }
}

__global__ __launch_bounds__(THREADS)
void fused_embed(const float* __restrict__ enc, const unsigned short* __restrict__ wsB,
                 const int* __restrict__ targ, float* __restrict__ out)
{
    __shared__ short sF[THREADS * D_];      // 32 KB bf16 feature tile, XOR-swizzled
    __shared__ float sCent[NSEG][D_ + 1];   // +1 pad: distinct banks per label
    __shared__ int   sCount[NSEG];
    __shared__ float sRed[4];

    const int tid  = threadIdx.x;
    const int lane = tid & 63, w = tid >> 6;
    const int l15  = lane & 15, g = lane >> 4;

    for (int i = tid; i < NSEG * (D_ + 1); i += THREADS) (&sCent[0][0])[i] = 0.f;
    if (tid < NSEG) sCount[tid] = 0;

    // B-fragments: 6 x 16B/lane, loaded once, live in VGPRs all kernel
    short8 b00 = *(const short8*)&wsB[(0 * 64 + lane) * 8];
    short8 b01 = *(const short8*)&wsB[(1 * 64 + lane) * 8];
    short8 b10 = *(const short8*)&wsB[(2 * 64 + lane) * 8];
    short8 b11 = *(const short8*)&wsB[(3 * 64 + lane) * 8];
    short8 b20 = *(const short8*)&wsB[(4 * 64 + lane) * 8];
    short8 b21 = *(const short8*)&wsB[(5 * 64 + lane) * 8];

    const int blk0 = blockIdx.x * BLKPIX;
    const int b    = blk0 / HW_;            // block never straddles images (2048 | 262144)
    float lossAcc = 0.f;
    __syncthreads();

    for (int t8 = 0; t8 < TILES; ++t8) {
        const int p = blk0 + t8 * THREADS + tid;          // this thread's pixel
        const float* fpx = enc + (size_t)b * D_ * HW_ + (p - b * HW_);
        const int lab = targ[p];

        // ---- stage: 64 channels in chunks of 8 -> bf16 swizzled LDS + f32 centroids ----
#pragma unroll 2
        for (int c0 = 0; c0 < D_; c0 += 8) {
            float g0 = fpx[(size_t)(c0 + 0) * HW_];
            float g1 = fpx[(size_t)(c0 + 1) * HW_];
            float g2 = fpx[(size_t)(c0 + 2) * HW_];
            float g3 = fpx[(size_t)(c0 + 3) * HW_];
            float g4 = fpx[(size_t)(c0 + 4) * HW_];
            float g5 = fpx[(size_t)(c0 + 5) * HW_];
            float g6 = fpx[(size_t)(c0 + 6) * HW_];
            float g7 = fpx[(size_t)(c0 + 7) * HW_];
            atomicAdd(&sCent[lab][c0 + 0], g0);
            atomicAdd(&sCent[lab][c0 + 1], g1);
            atomicAdd(&sCent[lab][c0 + 2], g2);
            atomicAdd(&sCent[lab][c0 + 3], g3);
            atomicAdd(&sCent[lab][c0 + 4], g4);
            atomicAdd(&sCent[lab][c0 + 5], g5);
            atomicAdd(&sCent[lab][c0 + 6], g6);
            atomicAdd(&sCent[lab][c0 + 7], g7);
            short8 v;
            v[0] = (short)f2bf(g0); v[1] = (short)f2bf(g1);
            v[2] = (short)f2bf(g2); v[3] = (short)f2bf(g3);
            v[4] = (short)f2bf(g4); v[5] = (short)f2bf(g5);
            v[6] = (short)f2bf(g6); v[7] = (short)f2bf(g7);
            // row = tid, unit = (c0/8) ^ (row&7)  -> bank-uniform b128 write
            *(short8*)&sF[(tid << 6) + ((((c0 >> 3) ^ (tid & 7))) << 3)] = v;
        }
        atomicAdd(&sCount[lab], 1);
        __syncthreads();

        // ---- MFMA: wave computes its 64 pixels x 48 labels ----
        f32x4 a00 = {0,0,0,0}, a01 = {0,0,0,0}, a02 = {0,0,0,0};
        f32x4 a10 = {0,0,0,0}, a11 = {0,0,0,0}, a12 = {0,0,0,0};
        f32x4 a20 = {0,0,0,0}, a21 = {0,0,0,0}, a22 = {0,0,0,0};
        f32x4 a30 = {0,0,0,0}, a31 = {0,0,0,0}, a32 = {0,0,0,0};

#define MSTEP(m, A0, A1, A2) { \
        const int pr = (w << 6) + ((m) << 4) + l15;  /* pr&7 == l15&7 */ \
        short8 af0 = *(const short8*)&sF[(pr << 6) + (((g)     ^ (l15 & 7)) << 3)]; \
        short8 af1 = *(const short8*)&sF[(pr << 6) + (((4 + g) ^ (l15 & 7)) << 3)]; \
        A0 = __builtin_amdgcn_mfma_f32_16x16x32_bf16(af0, b00, A0, 0, 0, 0); \
        A0 = __builtin_amdgcn_mfma_f32_16x16x32_bf16(af1, b01, A0, 0, 0, 0); \
        A1 = __builtin_amdgcn_mfma_f32_16x16x32_bf16(af0, b10, A1, 0, 0, 0); \
        A1 = __builtin_amdgcn_mfma_f32_16x16x32_bf16(af1, b11, A1, 0, 0, 0); \
        A2 = __builtin_amdgcn_mfma_f32_16x16x32_bf16(af0, b20, A2, 0, 0, 0); \
        A2 = __builtin_amdgcn_mfma_f32_16x16x32_bf16(af1, b21, A2, 0, 0, 0); }
        MSTEP(0, a00, a01, a02)
        MSTEP(1, a10, a11, a12)
        MSTEP(2, a20, a21, a22)
        MSTEP(3, a30, a31, a32)
#undef MSTEP

        // ---- entropy epilogue: C col = l15 (label), row = g*4+i (pixel) [m89 layout] ----
        // t=0 cols 0..15: within. t=1 col 16+l15: within if l15<3 else cross. t=2: valid l15<13.
#define ENTROPY(A0, A1, A2) { \
        _Pragma("unroll") \
        for (int i = 0; i < 4; ++i) { \
            float x0 = A0[i], x1 = A1[i], x2 = A2[i]; \
            float e0 = __expf(x0), e1 = __expf(x1), e2 = __expf(x2); \
            bool w1 = (l15 < 3), v2 = (l15 < 13); \
            float sw = e0 + (w1 ? e1 : 0.f); \
            float ww = x0 * e0 + (w1 ? x1 * e1 : 0.f); \
            float sc = (w1 ? 0.f : e1) + (v2 ? e2 : 0.f); \
            float wc = (w1 ? 0.f : x1 * e1) + (v2 ? x2 * e2 : 0.f); \
            _Pragma("unroll") \
            for (int off = 1; off < 16; off <<= 1) { \
                sw += __shfl_xor(sw, off, 16); ww += __shfl_xor(ww, off, 16); \
                sc += __shfl_xor(sc, off, 16); wc += __shfl_xor(wc, off, 16); } \
            if (l15 == 0) lossAcc += (__logf(sw) - ww / sw) + (__logf(sc) - wc / sc); \
        } }
        ENTROPY(a00, a01, a02)
        ENTROPY(a10, a11, a12)
        ENTROPY(a20, a21, a22)
        ENTROPY(a30, a31, a32)
#undef ENTROPY
        __syncthreads();   // sF safe to overwrite next tile; last iter: sCent complete
    }

    // ---- loss reduce: only lanes with l15==0 carry data ----
#pragma unroll
    for (int off = 32; off; off >>= 1) lossAcc += __shfl_down(lossAcc, off);
    if (lane == 0) sRed[w] = lossAcc;
    __syncthreads();
    if (tid == 0) {
        float s = sRed[0] + sRed[1] + sRed[2] + sRed[3];
        atomicAdd(out, s * (0.5f / (float)NPIX));
    }

    // ---- flush centroids + counts (512 blocks -> 8x fewer atomics than before) ----
    for (int i = tid; i < NSEG * D_; i += THREADS) {
        int n = i >> 6, d = i & 63;
        atomicAdd(&out[1 + i], sCent[n][d]);
    }
    if (tid < NSEG) atomicAdd(&out[1 + NSEG * D_ + tid], (float)sCount[tid]);
}

extern "C" void kernel_launch(void* const* d_in, const int* in_sizes, int n_in,
                              void* d_out, int out_size, void* d_ws, size_t ws_size,
                              hipStream_t stream) {
    const float* enc = (const float*)d_in[0];
    const float* wW  = (const float*)d_in[1];
    const float* wC  = (const float*)d_in[2];
    const int*   targ = (const int*)d_in[3];
    float* out = (float*)d_out;
    unsigned short* wsB = (unsigned short*)d_ws;   // 3072 * 2 B = 6 KB

    // out is poisoned 0xAA once and never re-poisoned; we accumulate with
    // atomics, so zero it every call (memset node is graph-capturable).
    hipMemsetAsync(d_out, 0, (size_t)out_size * sizeof(float), stream);

    prep_b<<<dim3(1), dim3(256), 0, stream>>>(wW, wC, wsB);
    fused_embed<<<dim3(NBLK), dim3(THREADS), 0, stream>>>(enc, wsB, targ, out);
}

// Round 8
// 380.910 us; speedup vs baseline: 1.1238x; 1.1238x over previous
//
#include <hip/hip_runtime.h>
#include <hip/hip_bf16.h>

#define HW_   (512 * 512)
#define B_    4
#define D_    64
#define NPIX  (B_ * HW_)          // 1048576
#define NW    19                  // within labels (20 - 1)
#define NC    26                  // cross labels  (27 - 1)
#define NSEG  20
#define SW_   20                  // padded stride of wTW rows (floats)
#define SC_   28                  // padded stride of wTC rows (floats)
#define THREADS 256

// ---- macro index lists (named scalars only) ----
#define L19(X) X(0)X(1)X(2)X(3)X(4)X(5)X(6)X(7)X(8)X(9)X(10)X(11)X(12)X(13)X(14)X(15)X(16)X(17)X(18)
#define L26(X) X(0)X(1)X(2)X(3)X(4)X(5)X(6)X(7)X(8)X(9)X(10)X(11)X(12)X(13)X(14)X(15)X(16)X(17)X(18)X(19)X(20)X(21)X(22)X(23)X(24)X(25)

// wTW[c][n] = wW[n][c] channel-major (contiguous per channel -> merged s_load)
__global__ void transpose_w(const float* __restrict__ wW, const float* __restrict__ wC,
                            float* __restrict__ ws) {
    int i = blockIdx.x * 256 + threadIdx.x;
    float* wTW = ws;                 // 64 * 20
    float* wTC = ws + D_ * SW_;      // 64 * 28
    if (i < D_ * SW_) {
        int c = i / SW_, n = i - c * SW_;
        wTW[i] = (n < NW) ? wW[n * D_ + c] : 0.f;
    }
    if (i < D_ * SC_) {
        int c = i / SC_, n = i - c * SC_;
        wTC[i] = (n < NC) ? wC[n * D_ + c] : 0.f;
    }
}

__global__ __launch_bounds__(THREADS)
void fused_embed(const float* __restrict__ enc, const float* __restrict__ ws,
                 const int* __restrict__ targ, float* __restrict__ out)
{
    const float* wTW = ws;
    const float* wTC = ws + D_ * SW_;

    __shared__ float sCent[NSEG][D_ + 1];   // +1 pad: bank = lab + c (mod 32)
    __shared__ int   sCount[NSEG];
    __shared__ float sRed[THREADS / 64];

    const int tid = threadIdx.x;
    for (int i = tid; i < NSEG * (D_ + 1); i += THREADS) (&sCent[0][0])[i] = 0.f;
    if (tid < NSEG) sCount[tid] = 0;
    __syncthreads();

    const int p   = blockIdx.x * THREADS + tid;    // 1 pixel per thread
    const int b   = (blockIdx.x * THREADS) / HW_;  // block never straddles images
    const int hw0 = p - b * HW_;
    const float* fp = enc + (size_t)b * (D_ * HW_) + hw0;
    const int lab = targ[p];

    // ========== PHASE A: centroids only (DS atomics; no SMEM in flight) ======
    // fire-and-forget ds_add_f32 -> nothing ever waits on lgkm here
#pragma unroll
    for (int c0 = 0; c0 < D_; c0 += 8) {
        float g0 = fp[(size_t)(c0 + 0) * HW_];
        float g1 = fp[(size_t)(c0 + 1) * HW_];
        float g2 = fp[(size_t)(c0 + 2) * HW_];
        float g3 = fp[(size_t)(c0 + 3) * HW_];
        float g4 = fp[(size_t)(c0 + 4) * HW_];
        float g5 = fp[(size_t)(c0 + 5) * HW_];
        float g6 = fp[(size_t)(c0 + 6) * HW_];
        float g7 = fp[(size_t)(c0 + 7) * HW_];
        atomicAdd(&sCent[lab][c0 + 0], g0);
        atomicAdd(&sCent[lab][c0 + 1], g1);
        atomicAdd(&sCent[lab][c0 + 2], g2);
        atomicAdd(&sCent[lab][c0 + 3], g3);
        atomicAdd(&sCent[lab][c0 + 4], g4);
        atomicAdd(&sCent[lab][c0 + 5], g5);
        atomicAdd(&sCent[lab][c0 + 6], g6);
        atomicAdd(&sCent[lab][c0 + 7], g7);
    }
    atomicAdd(&sCount[lab], 1);

    float lossAcc = 0.f;

    // ========== PHASE B pass 1: within, 19 accs (SMEM weights; NO DS ops) ====
    {
#define DECL(n) float a##n = 0.f;
        L19(DECL)
#undef DECL
#pragma unroll 1
        for (int c = 0; c < D_; c += 2) {
            float f0 = fp[(size_t)c * HW_];          // L3/L2 re-read
            float f1 = fp[(size_t)(c + 1) * HW_];
            const float* r0 = wTW + c * SW_;         // uniform -> merged s_load
            const float* r1 = r0 + SW_;
#define FMA2(n) { a##n = fmaf(r0[n], f0, a##n); a##n = fmaf(r1[n], f1, a##n); }
            L19(FMA2)
#undef FMA2
        }
        // entropy, no max-shift (logits ~ N(0,1); validated R5/R6)
        float S = 0.f, Wt = 0.f;
#define ES(n) { float e = __expf(a##n); S += e; Wt = fmaf(e, a##n, Wt); }
        L19(ES)
#undef ES
        lossAcc += __logf(S) - Wt / S;
    }

    // ========== PHASE B pass 2: cross, 26 accs ===============================
    {
#define DECL(n) float a##n = 0.f;
        L26(DECL)
#undef DECL
#pragma unroll 1
        for (int c = 0; c < D_; c += 2) {
            float f0 = fp[(size_t)c * HW_];
            float f1 = fp[(size_t)(c + 1) * HW_];
            const float* r0 = wTC + c * SC_;
            const float* r1 = r0 + SC_;
#define FMA2(n) { a##n = fmaf(r0[n], f0, a##n); a##n = fmaf(r1[n], f1, a##n); }
            L26(FMA2)
#undef FMA2
        }
        float S = 0.f, Wt = 0.f;
#define ES(n) { float e = __expf(a##n); S += e; Wt = fmaf(e, a##n, Wt); }
        L26(ES)
#undef ES
        lossAcc += __logf(S) - Wt / S;
    }

    // ---- wave + block reduce of loss ----
#pragma unroll
    for (int off = 32; off; off >>= 1) lossAcc += __shfl_down(lossAcc, off);
    if ((tid & 63) == 0) sRed[tid >> 6] = lossAcc;
    __syncthreads();
    if (tid == 0) {
        float s = 0.f;
#pragma unroll
        for (int w = 0; w < THREADS / 64; ++w) s += sRed[w];
        atomicAdd(out, s * (0.5f / (float)NPIX));
    }

    // ---- flush centroids + counts (counts as float; harness reads f32) ----
    for (int i = tid; i < NSEG * D_; i += THREADS) {
        int n = i >> 6, d = i & 63;
        atomicAdd(&out[1 + i], sCent[n][d]);
    }
    if (tid < NSEG) atomicAdd(&out[1 + NSEG * D_ + tid], (float)sCount[tid]);
}

extern "C" void kernel_launch(void* const* d_in, const int* in_sizes, int n_in,
                              void* d_out, int out_size, void* d_ws, size_t ws_size,
                              hipStream_t stream) {
    const float* enc = (const float*)d_in[0];
    const float* wW  = (const float*)d_in[1];
    const float* wC  = (const float*)d_in[2];
    const int*   targ = (const int*)d_in[3];
    float* out = (float*)d_out;
    float* ws  = (float*)d_ws;                 // (64*20 + 64*28) * 4 = 12288 B

    // d_out poisoned 0xAA once, never re-poisoned; we accumulate with atomics,
    // so zero it every call (memset node is graph-capturable).
    hipMemsetAsync(d_out, 0, (size_t)out_size * sizeof(float), stream);

    transpose_w<<<dim3((D_ * SC_ + 255) / 256), dim3(256), 0, stream>>>(wW, wC, ws);
    fused_embed<<<dim3(NPIX / THREADS), dim3(THREADS), 0, stream>>>(enc, ws, targ, out);
}